// Round 1
// baseline (2351.321 us; speedup 1.0000x reference)
//
#include <hip/hip_runtime.h>
#include <math.h>

#define T_ 256
#define B_ 32
#define E_ 256
#define HD_ 256
#define NG_ 1024
#define K_ 12
#define START_ 10
#define STOP_ 11
#define NEG_ -10000.0f

__device__ __forceinline__ float sigf(float x) { return 1.0f / (1.0f + expf(-x)); }

// ---------- token gather (bwd dir reversed within each sequence length) ----------
__global__ void tok_gather(const int* __restrict__ sent, const int* __restrict__ lens,
                           int* __restrict__ tokA) {
    int e = blockIdx.x * 256 + threadIdx.x;      // 0..16383 = [dir][t*32+b]
    int dir = e >> 13, m = e & 8191, t = m >> 5, b = m & 31;
    int len = lens[b];
    int tt = dir ? (t < len ? len - 1 - t : t) : t;
    tokA[e] = sent[b * T_ + tt];
}

// ---------- Whh^T into [dir][k][u*4+gate] (unit-major gate packing) ----------
__global__ void whh_tr(const float* __restrict__ Wf, const float* __restrict__ Wb,
                       float* __restrict__ WT) {
    int dir = blockIdx.x >> 8, k = blockIdx.x & 255, u = threadIdx.x;
    const float* W = dir ? Wb : Wf;
    float4 v;
    v.x = W[(0 * HD_ + u) * HD_ + k];   // i
    v.y = W[(1 * HD_ + u) * HD_ + k];   // f
    v.z = W[(2 * HD_ + u) * HD_ + k];   // g
    v.w = W[(3 * HD_ + u) * HD_ + k];   // o
    ((float4*)(WT + ((size_t)dir * 256 + k) * NG_))[u] = v;
}

// ---------- fused embedding-gather + input GEMM: G[dir][t*32+b][u*4+g] = x@Wih^T + bih + bhh ----------
__global__ __launch_bounds__(256) void in_gemm(
    const float* __restrict__ emb, const int* __restrict__ tokA,
    const float* __restrict__ Wih_f, const float* __restrict__ Wih_b,
    const float* __restrict__ bih_f, const float* __restrict__ bhh_f,
    const float* __restrict__ bih_b, const float* __restrict__ bhh_b,
    float* __restrict__ G) {
    const int dir = blockIdx.z;
    const int n0 = blockIdx.x * 128, m0 = blockIdx.y * 128;
    const float* Wih = dir ? Wih_b : Wih_f;
    const float* bihp = dir ? bih_b : bih_f;
    const float* bhhp = dir ? bhh_b : bhh_f;
    __shared__ float As[8][128];
    __shared__ float Bs[8][128];
    const int tid = threadIdx.x;
    const int rs = tid >> 1, kc = (tid & 1) * 4;
    const int tok = tokA[dir * 8192 + m0 + rs];
    const float* arow = emb + (size_t)tok * E_;
    const int np = n0 + rs;
    const int wrow = ((np & 3) << 8) | (np >> 2);     // permuted col n'=u*4+g -> Wih row g*256+u
    const float* brow = Wih + (size_t)wrow * E_;
    const int ty = tid >> 4, tx = tid & 15;

    float acc[8][8];
#pragma unroll
    for (int i = 0; i < 8; ++i)
#pragma unroll
        for (int j = 0; j < 8; ++j) acc[i][j] = 0.f;

    for (int k0 = 0; k0 < E_; k0 += 8) {
        float4 av = *(const float4*)(arow + k0 + kc);
        float4 bv = *(const float4*)(brow + k0 + kc);
        __syncthreads();
        As[kc + 0][rs] = av.x; As[kc + 1][rs] = av.y; As[kc + 2][rs] = av.z; As[kc + 3][rs] = av.w;
        Bs[kc + 0][rs] = bv.x; Bs[kc + 1][rs] = bv.y; Bs[kc + 2][rs] = bv.z; Bs[kc + 3][rs] = bv.w;
        __syncthreads();
#pragma unroll
        for (int k = 0; k < 8; ++k) {
            float4 a0 = *(const float4*)&As[k][ty * 8];
            float4 a1 = *(const float4*)&As[k][ty * 8 + 4];
            float4 b0 = *(const float4*)&Bs[k][tx * 8];
            float4 b1 = *(const float4*)&Bs[k][tx * 8 + 4];
            float af8[8] = {a0.x, a0.y, a0.z, a0.w, a1.x, a1.y, a1.z, a1.w};
            float bf8[8] = {b0.x, b0.y, b0.z, b0.w, b1.x, b1.y, b1.z, b1.w};
#pragma unroll
            for (int i = 0; i < 8; ++i)
#pragma unroll
                for (int j = 0; j < 8; ++j) acc[i][j] += af8[i] * bf8[j];
        }
    }
    float bias[8];
#pragma unroll
    for (int j = 0; j < 8; ++j) {
        int nn = n0 + tx * 8 + j;
        int wr = ((nn & 3) << 8) | (nn >> 2);
        bias[j] = bihp[wr] + bhhp[wr];
    }
#pragma unroll
    for (int i = 0; i < 8; ++i) {
        int m = m0 + ty * 8 + i;
        float* gp = G + ((size_t)dir * 8192 + m) * NG_ + n0 + tx * 8;
        float4 o0 = {acc[i][0] + bias[0], acc[i][1] + bias[1], acc[i][2] + bias[2], acc[i][3] + bias[3]};
        float4 o1 = {acc[i][4] + bias[4], acc[i][5] + bias[5], acc[i][6] + bias[6], acc[i][7] + bias[7]};
        *(float4*)gp = o0;
        *(float4*)(gp + 4) = o1;
    }
}

// ---------- recurrence: one WG per (dir, batch); no inter-WG sync ----------
__global__ __launch_bounds__(256) void lstm_rec(
    const float* __restrict__ WhhT, const float* __restrict__ G,
    const float* __restrict__ h0, const float* __restrict__ c0,
    const int* __restrict__ lens, float* __restrict__ hout) {
    const int dir = blockIdx.x >> 5, b = blockIdx.x & 31;
    const int tid = threadIdx.x;                   // thread = hidden unit
    __shared__ float hb2[2][HD_];
    const float4* WT = (const float4*)(WhhT + (size_t)dir * 256 * NG_);  // [k][u] float4 = 4 gates
    const float* Gd = G + (size_t)dir * 8192 * NG_;
    float c = c0[(dir * B_ + b) * HD_ + tid];
    hb2[0][tid] = h0[(dir * B_ + b) * HD_ + tid];
    const int len = lens[b];
    float* hO = hout + ((size_t)(dir * B_ + b)) * T_ * HD_;
    __syncthreads();
    int pp = 0;
    for (int t = 0; t < T_; ++t) {
        float4 g4 = ((const float4*)(Gd + ((size_t)t * B_ + b) * NG_))[tid];
        float ai = g4.x, af = g4.y, ag = g4.z, ao = g4.w;
        const float* hcur = hb2[pp];
#pragma unroll 8
        for (int k = 0; k < HD_; ++k) {
            float hk = hcur[k];                    // LDS broadcast
            float4 w = WT[(k << 8) + tid];         // coalesced 4KB/row from L2
            ai += w.x * hk; af += w.y * hk; ag += w.z * hk; ao += w.w * hk;
        }
        c = sigf(af) * c + sigf(ai) * tanhf(ag);
        float h = sigf(ao) * tanhf(c);
        hb2[pp ^ 1][tid] = h;
        int tt = dir ? (t < len ? len - 1 - t : t) : t;  // un-reverse bwd on store
        hO[tt * HD_ + tid] = h;
        pp ^= 1;
        __syncthreads();
    }
}

// ---------- features: feats[b*T+t][k] = hcat . W_out[k] + b_out[k] ----------
__global__ void feat_k(const float* __restrict__ hout, const float* __restrict__ Wout,
                       const float* __restrict__ bout, float* __restrict__ feats) {
    int tid = threadIdx.x;                 // 192 = 16 pos x 12 tags
    int pl = tid / 12, k = tid % 12;
    int p = blockIdx.x * 16 + pl;          // p = b*256 + t
    const float4* hf = (const float4*)(hout + (size_t)p * HD_);
    const float4* hb = (const float4*)(hout + (size_t)(B_ * T_ + p) * HD_);
    const float4* w0 = (const float4*)(Wout + (size_t)k * 512);
    const float4* w1 = (const float4*)(Wout + (size_t)k * 512 + 256);
    float acc = bout[k];
#pragma unroll 4
    for (int j = 0; j < 64; ++j) {
        float4 h4 = hf[j], v4 = w0[j];
        acc += h4.x * v4.x + h4.y * v4.y + h4.z * v4.z + h4.w * v4.w;
    }
#pragma unroll 4
    for (int j = 0; j < 64; ++j) {
        float4 h4 = hb[j], v4 = w1[j];
        acc += h4.x * v4.x + h4.y * v4.y + h4.z * v4.z + h4.w * v4.w;
    }
    feats[(size_t)p * K_ + k] = acc;
}

// ---------- Viterbi + backtrace: single block, bp nibble-packed in LDS ----------
__global__ __launch_bounds__(512) void viterbi_k(
    const float* __restrict__ feats, const float* __restrict__ trans,
    const int* __restrict__ lens, float* __restrict__ out) {
    __shared__ float fv[2][B_][16];
    __shared__ float tl[K_][16];
    __shared__ unsigned char bp[T_][B_][6];    // 4-bit backpointers, 48KB
    __shared__ int best_last[B_];
    int tid = threadIdx.x;
    int b = tid >> 4, lane = tid & 15;
    if (tid < K_ * K_) tl[tid / 12][tid % 12] = trans[tid];
    if (lane < K_) fv[0][b][lane] = (lane == START_) ? 0.f : NEG_;
    __syncthreads();
    int len = lens[b];
    int pp = 0;
    for (int t = 0; t < T_; ++t) {
        if (lane < K_) {
            float best = fv[pp][b][0] + tl[lane][0];
            int argp = 0;
#pragma unroll
            for (int p = 1; p < K_; ++p) {
                float v = fv[pp][b][p] + tl[lane][p];
                if (v > best) { best = v; argp = p; }   // strict > = first-max (matches jnp.argmax)
            }
            float nb = best + feats[((size_t)b * T_ + t) * K_ + lane];
            fv[pp ^ 1][b][lane] = (t < len) ? nb : fv[pp][b][lane];
            int other = __shfl_xor(argp, 1);
            if ((lane & 1) == 0) bp[t][b][lane >> 1] = (unsigned char)(argp | (other << 4));
        }
        __syncthreads();
        pp ^= 1;
    }
    if (lane == 0) {
        float best = fv[pp][b][0] + tl[STOP_][0];
        int bl = 0;
#pragma unroll
        for (int p = 1; p < K_; ++p) {
            float v = fv[pp][b][p] + tl[STOP_][p];
            if (v > best) { best = v; bl = p; }
        }
        out[b] = best;
        best_last[b] = bl;
    }
    __syncthreads();
    if (lane == 0) {
        int tag = best_last[b];
        for (int t = T_ - 1; t >= 0; --t) {
            int m = (t < len);
            out[B_ + b * T_ + t] = (float)(m ? tag : -1);
            if (m) tag = (bp[t][b][tag >> 1] >> ((tag & 1) * 4)) & 15;
        }
    }
}

extern "C" void kernel_launch(void* const* d_in, const int* in_sizes, int n_in,
                              void* d_out, int out_size, void* d_ws, size_t ws_size,
                              hipStream_t stream) {
    const int*   sent  = (const int*)d_in[0];
    const int*   lens  = (const int*)d_in[1];
    const float* emb   = (const float*)d_in[2];
    const float* Wih_f = (const float*)d_in[3];
    const float* Whh_f = (const float*)d_in[4];
    const float* bih_f = (const float*)d_in[5];
    const float* bhh_f = (const float*)d_in[6];
    const float* Wih_b = (const float*)d_in[7];
    const float* Whh_b = (const float*)d_in[8];
    const float* bih_b = (const float*)d_in[9];
    const float* bhh_b = (const float*)d_in[10];
    const float* h0    = (const float*)d_in[11];
    const float* c0    = (const float*)d_in[12];
    const float* Wout  = (const float*)d_in[13];
    const float* bout  = (const float*)d_in[14];
    const float* trans = (const float*)d_in[15];
    float* out = (float*)d_out;

    char* ws = (char*)d_ws;
    int*   tokA  = (int*)ws;                                            // 65536 B
    float* WhhT  = (float*)(ws + 65536);                                // 2 MB
    float* G     = (float*)(ws + 65536 + 2097152);                      // 67.1 MB
    float* hout  = (float*)(ws + 65536 + 2097152 + 67108864);           // 16.8 MB
    float* feats = (float*)(ws + 65536 + 2097152 + 67108864 + 16777216);// 0.39 MB

    tok_gather<<<64, 256, 0, stream>>>(sent, lens, tokA);
    whh_tr<<<512, 256, 0, stream>>>(Whh_f, Whh_b, WhhT);
    in_gemm<<<dim3(8, 64, 2), 256, 0, stream>>>(emb, tokA, Wih_f, Wih_b,
                                                bih_f, bhh_f, bih_b, bhh_b, G);
    lstm_rec<<<64, 256, 0, stream>>>(WhhT, G, h0, c0, lens, hout);
    feat_k<<<512, 192, 0, stream>>>(hout, Wout, bout, feats);
    viterbi_k<<<1, 512, 0, stream>>>(feats, trans, lens, out);
}

// Round 2
// 1684.129 us; speedup vs baseline: 1.3962x; 1.3962x over previous
//
#include <hip/hip_runtime.h>
#include <math.h>

#define T_ 256
#define B_ 32
#define E_ 256
#define HD_ 256
#define NG_ 1024
#define K_ 12
#define START_ 10
#define STOP_ 11
#define NEG_ -10000.0f

__device__ __forceinline__ float sigf(float x) { return 1.0f / (1.0f + expf(-x)); }

// ---------- token gather (bwd dir reversed within each sequence length) ----------
__global__ void tok_gather(const int* __restrict__ sent, const int* __restrict__ lens,
                           int* __restrict__ tokA) {
    int e = blockIdx.x * 256 + threadIdx.x;      // 0..16383 = [dir][t*32+b]
    int dir = e >> 13, m = e & 8191, t = m >> 5, b = m & 31;
    int len = lens[b];
    int tt = dir ? (t < len ? len - 1 - t : t) : t;
    tokA[e] = sent[b * T_ + tt];
}

// ---------- Whh^T into [dir][k][u*4+gate] (unit-major gate packing) ----------
__global__ void whh_tr(const float* __restrict__ Wf, const float* __restrict__ Wb,
                       float* __restrict__ WT) {
    int dir = blockIdx.x >> 8, k = blockIdx.x & 255, u = threadIdx.x;
    const float* W = dir ? Wb : Wf;
    float4 v;
    v.x = W[(0 * HD_ + u) * HD_ + k];   // i
    v.y = W[(1 * HD_ + u) * HD_ + k];   // f
    v.z = W[(2 * HD_ + u) * HD_ + k];   // g
    v.w = W[(3 * HD_ + u) * HD_ + k];   // o
    ((float4*)(WT + ((size_t)dir * 256 + k) * NG_))[u] = v;
}

// ---------- zero the sync flags (ws is poisoned 0xAA before every launch) ----------
__global__ void init_flags(int* __restrict__ flags) {
    flags[threadIdx.x] = 0;   // 64 flags
}

// ---------- fused embedding-gather + input GEMM: G[dir][t*32+b][u*4+g] = x@Wih^T + bih + bhh ----------
__global__ __launch_bounds__(256) void in_gemm(
    const float* __restrict__ emb, const int* __restrict__ tokA,
    const float* __restrict__ Wih_f, const float* __restrict__ Wih_b,
    const float* __restrict__ bih_f, const float* __restrict__ bhh_f,
    const float* __restrict__ bih_b, const float* __restrict__ bhh_b,
    float* __restrict__ G) {
    const int dir = blockIdx.z;
    const int n0 = blockIdx.x * 128, m0 = blockIdx.y * 128;
    const float* Wih = dir ? Wih_b : Wih_f;
    const float* bihp = dir ? bih_b : bih_f;
    const float* bhhp = dir ? bhh_b : bhh_f;
    __shared__ float As[8][128];
    __shared__ float Bs[8][128];
    const int tid = threadIdx.x;
    const int rs = tid >> 1, kc = (tid & 1) * 4;
    const int tok = tokA[dir * 8192 + m0 + rs];
    const float* arow = emb + (size_t)tok * E_;
    const int np = n0 + rs;
    const int wrow = ((np & 3) << 8) | (np >> 2);     // permuted col n'=u*4+g -> Wih row g*256+u
    const float* brow = Wih + (size_t)wrow * E_;
    const int ty = tid >> 4, tx = tid & 15;

    float acc[8][8];
#pragma unroll
    for (int i = 0; i < 8; ++i)
#pragma unroll
        for (int j = 0; j < 8; ++j) acc[i][j] = 0.f;

    for (int k0 = 0; k0 < E_; k0 += 8) {
        float4 av = *(const float4*)(arow + k0 + kc);
        float4 bv = *(const float4*)(brow + k0 + kc);
        __syncthreads();
        As[kc + 0][rs] = av.x; As[kc + 1][rs] = av.y; As[kc + 2][rs] = av.z; As[kc + 3][rs] = av.w;
        Bs[kc + 0][rs] = bv.x; Bs[kc + 1][rs] = bv.y; Bs[kc + 2][rs] = bv.z; Bs[kc + 3][rs] = bv.w;
        __syncthreads();
#pragma unroll
        for (int k = 0; k < 8; ++k) {
            float4 a0 = *(const float4*)&As[k][ty * 8];
            float4 a1 = *(const float4*)&As[k][ty * 8 + 4];
            float4 b0 = *(const float4*)&Bs[k][tx * 8];
            float4 b1 = *(const float4*)&Bs[k][tx * 8 + 4];
            float af8[8] = {a0.x, a0.y, a0.z, a0.w, a1.x, a1.y, a1.z, a1.w};
            float bf8[8] = {b0.x, b0.y, b0.z, b0.w, b1.x, b1.y, b1.z, b1.w};
#pragma unroll
            for (int i = 0; i < 8; ++i)
#pragma unroll
                for (int j = 0; j < 8; ++j) acc[i][j] += af8[i] * bf8[j];
        }
    }
    float bias[8];
#pragma unroll
    for (int j = 0; j < 8; ++j) {
        int nn = n0 + tx * 8 + j;
        int wr = ((nn & 3) << 8) | (nn >> 2);
        bias[j] = bihp[wr] + bhhp[wr];
    }
#pragma unroll
    for (int i = 0; i < 8; ++i) {
        int m = m0 + ty * 8 + i;
        float* gp = G + ((size_t)dir * 8192 + m) * NG_ + n0 + tx * 8;
        float4 o0 = {acc[i][0] + bias[0], acc[i][1] + bias[1], acc[i][2] + bias[2], acc[i][3] + bias[3]};
        float4 o1 = {acc[i][4] + bias[4], acc[i][5] + bias[5], acc[i][6] + bias[6], acc[i][7] + bias[7]};
        *(float4*)gp = o0;
        *(float4*)(gp + 4) = o1;
    }
}

// ---------- recurrence v2: WG = (dir, unit-tile of 32, batch-tile of 8); 64 WGs ----------
// Per step: W-slice 128KB from L2 (amortized over 8 batches), cross-WG h exchange via
// agent-scope (sc1) atomics through a 2-deep global buffer + monotone flags.
__global__ __launch_bounds__(512) void lstm_rec2(
    const float* __restrict__ WhhT, const float* __restrict__ G,
    const float* __restrict__ h0, const float* __restrict__ c0,
    const int* __restrict__ lens, float* __restrict__ hout,
    float* __restrict__ hex, int* __restrict__ flags) {
    const int wg = blockIdx.x;                   // dir*32 + bt*8 + ut
    const int dir = wg >> 5, bt = (wg >> 3) & 3, ut = wg & 7;
    const int tid = threadIdx.x;
    const int u = tid & 31;                      // unit within tile
    const int ks = tid >> 5;                     // k-slice 0..15 (16 k each)
    const int fb = tid >> 5;                     // (tid<256 only) batch within tile

    __shared__ float hs[256 * 8];                // h(t-1): [k][b], b fast
    __shared__ float red[256 * 33];              // ks-partial reduction, pitch 33

    // group max length (identical across the 8 WGs of the group)
    int Tmax = 1;
#pragma unroll
    for (int b = 0; b < 8; ++b) { int l = lens[bt * 8 + b]; if (l > Tmax) Tmax = l; }

    float c = 0.f; int len_b = 0;
    if (tid < 256) {
        int bg = bt * 8 + fb;
        c = c0[(dir * B_ + bg) * HD_ + ut * 32 + u];
        len_b = lens[bg];
    }
    // stage h0 -> hs[k][b]
    if (tid < 256) {
        int k = tid;
#pragma unroll
        for (int b = 0; b < 8; ++b) hs[k * 8 + b] = h0[(dir * B_ + bt * 8 + b) * HD_ + k];
    }
    __syncthreads();

    const float4* WT4 = (const float4*)(WhhT + (size_t)dir * 256 * NG_);
    const float* Gd = G + (size_t)dir * 8192 * NG_;
    float* hexg = hex + (size_t)(dir * 4 + bt) * 2 * 2048;   // [parity][k][b]
    const int gbase = (dir * 4 + bt) * 8;

    for (int t = 0; t < Tmax; ++t) {
        if (t > 0) {
            // wait for all 8 unit-tile peers to have published h(t-1)
            if (tid < 8) {
                int iter = 0;
                while (__hip_atomic_load(&flags[gbase + tid], __ATOMIC_RELAXED,
                                         __HIP_MEMORY_SCOPE_AGENT) < t) {
                    __builtin_amdgcn_s_sleep(2);
                    if (++iter > (1 << 22)) break;       // bail -> visible failure, not hang
                }
            }
            __syncthreads();
            // stage h(t-1) from the exchange buffer
            float* src = hexg + ((t - 1) & 1) * 2048;
            int i = tid * 4;
            float a0 = __hip_atomic_load(&src[i + 0], __ATOMIC_RELAXED, __HIP_MEMORY_SCOPE_AGENT);
            float a1 = __hip_atomic_load(&src[i + 1], __ATOMIC_RELAXED, __HIP_MEMORY_SCOPE_AGENT);
            float a2 = __hip_atomic_load(&src[i + 2], __ATOMIC_RELAXED, __HIP_MEMORY_SCOPE_AGENT);
            float a3 = __hip_atomic_load(&src[i + 3], __ATOMIC_RELAXED, __HIP_MEMORY_SCOPE_AGENT);
            hs[i + 0] = a0; hs[i + 1] = a1; hs[i + 2] = a2; hs[i + 3] = a3;
            __syncthreads();
        }

        // ---- recurrent GEMM slice: acc[b] (4 gates) over this thread's 16 k ----
        float4 acc[8];
#pragma unroll
        for (int b = 0; b < 8; ++b) acc[b] = make_float4(0.f, 0.f, 0.f, 0.f);
        const float4* hs4 = (const float4*)hs;
        const int kbase = ks * 16;
#pragma unroll 4
        for (int j = 0; j < 16; ++j) {
            int k = kbase + j;
            float4 w = WT4[(k << 8) + ut * 32 + u];   // streamed from L2, coalesced
            float4 hA = hs4[k * 2 + 0];               // h[k][b0..3] broadcast
            float4 hB = hs4[k * 2 + 1];               // h[k][b4..7] broadcast
            acc[0].x += w.x * hA.x; acc[0].y += w.y * hA.x; acc[0].z += w.z * hA.x; acc[0].w += w.w * hA.x;
            acc[1].x += w.x * hA.y; acc[1].y += w.y * hA.y; acc[1].z += w.z * hA.y; acc[1].w += w.w * hA.y;
            acc[2].x += w.x * hA.z; acc[2].y += w.y * hA.z; acc[2].z += w.z * hA.z; acc[2].w += w.w * hA.z;
            acc[3].x += w.x * hA.w; acc[3].y += w.y * hA.w; acc[3].z += w.z * hA.w; acc[3].w += w.w * hA.w;
            acc[4].x += w.x * hB.x; acc[4].y += w.y * hB.x; acc[4].z += w.z * hB.x; acc[4].w += w.w * hB.x;
            acc[5].x += w.x * hB.y; acc[5].y += w.y * hB.y; acc[5].z += w.z * hB.y; acc[5].w += w.w * hB.y;
            acc[6].x += w.x * hB.z; acc[6].y += w.y * hB.z; acc[6].z += w.z * hB.z; acc[6].w += w.w * hB.z;
            acc[7].x += w.x * hB.w; acc[7].y += w.y * hB.w; acc[7].z += w.z * hB.w; acc[7].w += w.w * hB.w;
        }

        // G pre-activation (includes both biases), issue early
        float4 g4 = make_float4(0.f, 0.f, 0.f, 0.f);
        if (tid < 256)
            g4 = ((const float4*)(Gd + ((size_t)t * B_ + bt * 8 + fb) * NG_))[ut * 32 + u];

        // ---- reduce the 16 k-slices: shfl pair-combine, then LDS tree ----
#pragma unroll
        for (int b = 0; b < 8; ++b) {
            acc[b].x += __shfl_xor(acc[b].x, 32);
            acc[b].y += __shfl_xor(acc[b].y, 32);
            acc[b].z += __shfl_xor(acc[b].z, 32);
            acc[b].w += __shfl_xor(acc[b].w, 32);
        }
        int wv = tid >> 6;                        // wave index 0..7
        if ((tid & 32) == 0) {
            float* r = &red[(wv * 32 + u) * 33];
#pragma unroll
            for (int b = 0; b < 8; ++b) {
                r[b * 4 + 0] = acc[b].x; r[b * 4 + 1] = acc[b].y;
                r[b * 4 + 2] = acc[b].z; r[b * 4 + 3] = acc[b].w;
            }
        }
        __syncthreads();

        if (tid < 256) {
            float si = g4.x, sf = g4.y, sg = g4.z, so = g4.w;
#pragma unroll
            for (int ww = 0; ww < 8; ++ww) {
                const float* r = &red[(ww * 32 + u) * 33 + fb * 4];
                si += r[0]; sf += r[1]; sg += r[2]; so += r[3];
            }
            c = sigf(sf) * c + sigf(si) * tanhf(sg);
            float h = sigf(so) * tanhf(c);
            int tt = dir ? (t < len_b ? len_b - 1 - t : t) : t;
            hout[(((size_t)(dir * B_ + bt * 8 + fb)) * T_ + tt) * HD_ + ut * 32 + u] = h;
            __hip_atomic_store(&hexg[(t & 1) * 2048 + (ut * 32 + u) * 8 + fb], h,
                               __ATOMIC_RELAXED, __HIP_MEMORY_SCOPE_AGENT);
        }
        __syncthreads();   // barrier drains each wave's vmcnt -> h stores complete
        if (tid == 0)
            __hip_atomic_store(&flags[gbase + ut], t + 1,
                               __ATOMIC_RELAXED, __HIP_MEMORY_SCOPE_AGENT);
    }
}

// ---------- features: feats[b*T+t][k] = hcat . W_out[k] + b_out[k] ----------
__global__ void feat_k(const float* __restrict__ hout, const float* __restrict__ Wout,
                       const float* __restrict__ bout, float* __restrict__ feats) {
    int tid = threadIdx.x;                 // 192 = 16 pos x 12 tags
    int pl = tid / 12, k = tid % 12;
    int p = blockIdx.x * 16 + pl;          // p = b*256 + t
    const float4* hf = (const float4*)(hout + (size_t)p * HD_);
    const float4* hb = (const float4*)(hout + (size_t)(B_ * T_ + p) * HD_);
    const float4* w0 = (const float4*)(Wout + (size_t)k * 512);
    const float4* w1 = (const float4*)(Wout + (size_t)k * 512 + 256);
    float acc = bout[k];
#pragma unroll 4
    for (int j = 0; j < 64; ++j) {
        float4 h4 = hf[j], v4 = w0[j];
        acc += h4.x * v4.x + h4.y * v4.y + h4.z * v4.z + h4.w * v4.w;
    }
#pragma unroll 4
    for (int j = 0; j < 64; ++j) {
        float4 h4 = hb[j], v4 = w1[j];
        acc += h4.x * v4.x + h4.y * v4.y + h4.z * v4.z + h4.w * v4.w;
    }
    feats[(size_t)p * K_ + k] = acc;
}

// ---------- Viterbi + backtrace: single block, bp nibble-packed in LDS ----------
__global__ __launch_bounds__(512) void viterbi_k(
    const float* __restrict__ feats, const float* __restrict__ trans,
    const int* __restrict__ lens, float* __restrict__ out) {
    __shared__ float fv[2][B_][16];
    __shared__ float tl[K_][16];
    __shared__ unsigned char bp[T_][B_][6];    // 4-bit backpointers, 48KB
    __shared__ int best_last[B_];
    int tid = threadIdx.x;
    int b = tid >> 4, lane = tid & 15;
    if (tid < K_ * K_) tl[tid / 12][tid % 12] = trans[tid];
    if (lane < K_) fv[0][b][lane] = (lane == START_) ? 0.f : NEG_;
    __syncthreads();
    int len = lens[b];
    int pp = 0;
    for (int t = 0; t < T_; ++t) {
        if (lane < K_) {
            float best = fv[pp][b][0] + tl[lane][0];
            int argp = 0;
#pragma unroll
            for (int p = 1; p < K_; ++p) {
                float v = fv[pp][b][p] + tl[lane][p];
                if (v > best) { best = v; argp = p; }   // strict > = first-max (matches jnp.argmax)
            }
            float nb = best + feats[((size_t)b * T_ + t) * K_ + lane];
            fv[pp ^ 1][b][lane] = (t < len) ? nb : fv[pp][b][lane];
            int other = __shfl_xor(argp, 1);
            if ((lane & 1) == 0) bp[t][b][lane >> 1] = (unsigned char)(argp | (other << 4));
        }
        __syncthreads();
        pp ^= 1;
    }
    if (lane == 0) {
        float best = fv[pp][b][0] + tl[STOP_][0];
        int bl = 0;
#pragma unroll
        for (int p = 1; p < K_; ++p) {
            float v = fv[pp][b][p] + tl[STOP_][p];
            if (v > best) { best = v; bl = p; }
        }
        out[b] = best;
        best_last[b] = bl;
    }
    __syncthreads();
    if (lane == 0) {
        int tag = best_last[b];
        for (int t = T_ - 1; t >= 0; --t) {
            int m = (t < len);
            out[B_ + b * T_ + t] = (float)(m ? tag : -1);
            if (m) tag = (bp[t][b][tag >> 1] >> ((tag & 1) * 4)) & 15;
        }
    }
}

extern "C" void kernel_launch(void* const* d_in, const int* in_sizes, int n_in,
                              void* d_out, int out_size, void* d_ws, size_t ws_size,
                              hipStream_t stream) {
    const int*   sent  = (const int*)d_in[0];
    const int*   lens  = (const int*)d_in[1];
    const float* emb   = (const float*)d_in[2];
    const float* Wih_f = (const float*)d_in[3];
    const float* Whh_f = (const float*)d_in[4];
    const float* bih_f = (const float*)d_in[5];
    const float* bhh_f = (const float*)d_in[6];
    const float* Wih_b = (const float*)d_in[7];
    const float* Whh_b = (const float*)d_in[8];
    const float* bih_b = (const float*)d_in[9];
    const float* bhh_b = (const float*)d_in[10];
    const float* h0    = (const float*)d_in[11];
    const float* c0    = (const float*)d_in[12];
    const float* Wout  = (const float*)d_in[13];
    const float* bout  = (const float*)d_in[14];
    const float* trans = (const float*)d_in[15];
    float* out = (float*)d_out;

    char* ws = (char*)d_ws;
    int*   tokA  = (int*)ws;                                            // 64 KB
    float* WhhT  = (float*)(ws + 65536);                                // 2 MB
    float* G     = (float*)(ws + 65536 + 2097152);                      // 67.1 MB
    float* hout  = (float*)(ws + 65536 + 2097152 + 67108864);           // 16.8 MB
    float* feats = (float*)(ws + 65536 + 2097152 + 67108864 + 16777216);// 0.39 MB
    float* hex   = (float*)(ws + 86441984);                             // 128 KB h-exchange
    int*   flags = (int*)(ws + 86441984 + 131072);                      // 256 B

    tok_gather<<<64, 256, 0, stream>>>(sent, lens, tokA);
    whh_tr<<<512, 256, 0, stream>>>(Whh_f, Whh_b, WhhT);
    init_flags<<<1, 64, 0, stream>>>(flags);
    in_gemm<<<dim3(8, 64, 2), 256, 0, stream>>>(emb, tokA, Wih_f, Wih_b,
                                                bih_f, bhh_f, bih_b, bhh_b, G);
    lstm_rec2<<<64, 512, 0, stream>>>(WhhT, G, h0, c0, lens, hout, hex, flags);
    feat_k<<<512, 192, 0, stream>>>(hout, Wout, bout, feats);
    viterbi_k<<<1, 512, 0, stream>>>(feats, trans, lens, out);
}